// Round 9
// baseline (675.379 us; speedup 1.0000x reference)
//
#include <hip/hip_runtime.h>

#define N_    64
#define CIN_  192
#define T_    256
#define V_    25
#define K_    3
#define COUT_ 64
#define OC_   192
#define SS_   5

#define OUT_OFF_A (N_*COUT_*T_*V_)          // 26214400
#define OUT_OFF_G (OUT_OFF_A + K_*V_*V_)    // 26216275

#define TCH   2              // t's per inner chunk
#define HCH   16             // chunks per block -> 32 t's per block
#define NCOLS 50             // TCH*V_
#define NCT   4              // 16-col tiles in GEMM1 (50 -> pad 64)
#define XB_STRIDE 200        // shorts per XB row (192 + 8 pad)
#define XB_ROWS 64           // NCT*16 (rows 50..63 stay zero from init)
#define XB_SH  (XB_ROWS*XB_STRIDE)            // 12800 shorts (single buffer)
#define YB_STRIDE 104        // shorts per YB row (75 -> pad 96 -> 104)
#define YB_ROWS 128          // TCH*64
#define YB_OFF  XB_SH
#define U_SHORTS (YB_OFF + YB_ROWS*YB_STRIDE) // 26112 shorts = 52224 B
#define NYV  4800            // OC_*V_ : per-n ybar size
#define CPN  (T_/(TCH*HCH))  // 8 chunk-blocks per n
#define NBLK (N_*CPN)        // 512 fused blocks = exactly 2/CU, one round
#define SUNITS (25*(CIN_/8)) // 600 staging units per chunk (col-pair x 8-ch group)
#define UPT 3                // ceil(SUNITS/256) units per thread

// Barrier that does NOT drain vmcnt: each wave drains its own LDS ops
// (lgkmcnt(0)) so producer ds_writes are visible after s_barrier, but
// in-flight global loads/stores stay outstanding across the barrier.
// sched_barrier(0) on both sides pins memory ops (rule #18).
#define BAR_LDS() do {                                          \
    __builtin_amdgcn_sched_barrier(0);                          \
    asm volatile("s_waitcnt lgkmcnt(0)" ::: "memory");          \
    __builtin_amdgcn_s_barrier();                               \
    __builtin_amdgcn_sched_barrier(0);                          \
} while (0)

typedef __attribute__((ext_vector_type(8))) short short8;
typedef __attribute__((ext_vector_type(4))) float float4v;

__device__ inline unsigned bf16r(float f) {            // fp32 -> bf16 RNE
    unsigned u = __float_as_uint(f);
    return (u + 0x7fffu + ((u >> 16) & 1u)) >> 16;
}

// ---------- prep: WcB (bf16), A2T (Acat^T, bf16, zero-padded), A copy, ysum=0 --
__global__ __launch_bounds__(256) void prep(const float* __restrict__ Wc,
                                            const float* __restrict__ A,
                                            short* __restrict__ WcB,
                                            short* __restrict__ A2T,
                                            float* __restrict__ ysum,
                                            float* __restrict__ out) {
    int idx = blockIdx.x * 256 + threadIdx.x;
    if (idx < OC_ * CIN_) WcB[idx] = (short)bf16r(Wc[idx]);
    if (idx < 32 * YB_STRIDE) {           // A2T[w][kk], kk = k*25+v, zeros elsewhere
        int w = idx / YB_STRIDE, kk = idx - w * YB_STRIDE;
        short val = 0;
        if (w < V_ && kk < K_ * V_) {
            int k = kk / V_, v = kk - k * V_;
            val = (short)bf16r(A[k * V_ * V_ + v * V_ + w]);
        }
        A2T[idx] = val;
    }
    if (idx < K_ * V_ * V_) out[OUT_OFF_A + idx] = A[idx];
    if (idx < N_ * NYV) ysum[idx] = 0.f;  // atomic accumulation target for fused
}

// ---------- fused MFMA: y = Wc@x+bc, out = Ycat@Acat, ybar sums in-register ----
// Pipelined staging (R6): chunk h+1's 24 global loads issue right after B0(h),
// pinned by sched_barrier(0). b2 reloaded per chunk (L2-hot). lgkmcnt-only
// barriers keep vmem in flight across B0/B1. No setprio (R7/R8 ablation).
// R9: the per-chunk LDS partials phase is DELETED. Each thread's acc[j][ct][i]
// maps to a FIXED (o, v) output coordinate across all chunks (t varies, but
// ysum sums over t anyway), so ybar accumulates in registers:
// racc2[j][ct][i] += acc[j][ct][i] at Ywrite time — zero LDS traffic — and is
// flushed once at kernel end (<=48 atomics/thread, 2-way collisions only).
// Pad-correctness: A2T cols [75,96) are exact zeros; XB rows 50..63 / YB pad
// cols keep the one-time zero init or finite bf16; invalid cols (>=50) are
// accumulated but never flushed.
__global__ __launch_bounds__(256, 2) void fused_mfma(const float* __restrict__ x,
                                                     const short* __restrict__ WcB,
                                                     const float* __restrict__ bc,
                                                     const short* __restrict__ A2T,
                                                     float* __restrict__ out,
                                                     float* __restrict__ ysum) {
    __shared__ __align__(16) short U[U_SHORTS];

    const int tid  = threadIdx.x;
    const int lane = tid & 63;
    const int wv   = tid >> 6;
    const int l15  = lane & 15;
    const int q    = lane >> 4;
    const int n    = blockIdx.x >> 3;
    const int tc   = blockIdx.x & 7;
    const int rt0  = wv * 3;

    // one-time zero: every byte of U is finite forever after
    {
        int4 z = make_int4(0, 0, 0, 0);
        for (int i = tid; i < U_SHORTS / 8; i += 256) ((int4*)U)[i] = z;
    }
    __syncthreads();

    // Wc A-fragments resident in registers (72 VGPR): wave wv owns rows [wv*48,+48)
    short8 wfrag[3][6];
    {
        const short* wb = WcB + (rt0 * 16 + l15) * CIN_ + q * 8;
#pragma unroll
        for (int j = 0; j < 3; ++j)
#pragma unroll
            for (int ks = 0; ks < 6; ++ks)
                wfrag[j][ks] = *(const short8*)(wb + j * 16 * CIN_ + ks * 32);
    }
    float4v bvec[3];
#pragma unroll
    for (int j = 0; j < 3; ++j)
        bvec[j] = *(const float4v*)(bc + (rt0 + j) * 16 + q * 4);

    // in-register ybar accumulators, acc-layout (48 f32)
    float4v racc2[3][NCT];
#pragma unroll
    for (int j = 0; j < 3; ++j)
#pragma unroll
        for (int ct = 0; ct < NCT; ++ct) racc2[j][ct] = (float4v){0.f, 0.f, 0.f, 0.f};

    const float* xn = x + (size_t)n * (CIN_ * T_ * V_);
    const int tbase = tc * (TCH * HCH);

    // prologue: stage chunk 0 (synchronous, once per block)
    for (int u = tid; u < SUNITS; u += 256) {
        int col2 = u % 25, cg = u / 25;
        const float* xp = xn + (size_t)(cg * 8) * (T_ * V_) + tbase * V_ + col2 * 2;
        short8 a, b;
#pragma unroll
        for (int j = 0; j < 8; ++j) {
            float2 f = *(const float2*)(xp + (size_t)j * (T_ * V_));
            a[j] = (short)bf16r(f.x);
            b[j] = (short)bf16r(f.y);
        }
        *(short8*)&U[(col2 * 2 + 0) * XB_STRIDE + cg * 8] = a;
        *(short8*)&U[(col2 * 2 + 1) * XB_STRIDE + cg * 8] = b;
    }

    for (int h = 0; h < HCH; ++h) {
        const int t0 = tbase + h * TCH;
        const bool stage_ok = (h < HCH - 1);

        BAR_LDS();         // B0: XB(h) ready; YB(h-1) readers done

        // ---- prefetch: issue chunk h+1's 24 global loads NOW, pinned ----
        float2 tmp[UPT][8];
        if (stage_ok) {
#pragma unroll
            for (int s = 0; s < UPT; ++s) {
                int u = tid + s * 256;
                if (u < SUNITS) {
                    int col2 = u % 25, cg = u / 25;
                    const float* xp = xn + (size_t)(cg * 8) * (T_ * V_) + (t0 + TCH) * V_ + col2 * 2;
#pragma unroll
                    for (int j = 0; j < 8; ++j)
                        tmp[s][j] = *(const float2*)(xp + (size_t)j * (T_ * V_));
                }
            }
            __builtin_amdgcn_sched_barrier(0);   // loads may not sink past here
        }

        // ---- GEMM1: acc[j][ct], K=192=6*32, wfrag resident ----
        float4v acc[3][NCT];
#pragma unroll
        for (int j = 0; j < 3; ++j)
#pragma unroll
            for (int ct = 0; ct < NCT; ++ct) acc[j][ct] = bvec[j];

#pragma unroll
        for (int ct = 0; ct < NCT; ++ct) {
            const short* xb = &U[(ct * 16 + l15) * XB_STRIDE + q * 8];
#pragma unroll
            for (int ks = 0; ks < 6; ++ks) {
                short8 bfrag = *(const short8*)(xb + ks * 32);
#pragma unroll
                for (int j = 0; j < 3; ++j)
                    acc[j][ct] = __builtin_amdgcn_mfma_f32_16x16x32_bf16(
                        wfrag[j][ks], bfrag, acc[j][ct], 0, 0, 0);
            }
        }

        // ---- Ywrite: acc -> YB[(tl*64+cc)][k*25+v]; ybar accumulate in-reg ----
#pragma unroll
        for (int ct = 0; ct < NCT; ++ct) {
            int col = ct * 16 + l15;
            if (col < NCOLS) {
                int tl = col / V_;
                int v  = col - tl * V_;
#pragma unroll
                for (int j = 0; j < 3; ++j) {
                    int obase = (rt0 + j) * 16 + q * 4;
#pragma unroll
                    for (int i = 0; i < 4; ++i) {
                        int o   = obase + i;
                        int row = tl * 64 + (o & 63);
                        int cY  = (o >> 6) * V_ + v;
                        U[YB_OFF + row * YB_STRIDE + cY] = (short)bf16r(acc[j][ct][i]);
                        racc2[j][ct][i] += acc[j][ct][i];   // ybar: pure register add
                    }
                }
            }
        }

        BAR_LDS();         // B1: YB(h) published; XB(h) readers done; vmem flies on

        // ---- GEMM2: Out[(t,cc)=128][w pad 32] = Ycat[128][pad96] @ Acat ----
        // b2 reloaded per chunk (L2-hot; frees 24 regs for the prefetch tmp)
        short8 b2[2][3];
#pragma unroll
        for (int nt = 0; nt < 2; ++nt)
#pragma unroll
            for (int ks = 0; ks < 3; ++ks)
                b2[nt][ks] = *(const short8*)&A2T[(nt * 16 + l15) * YB_STRIDE + ks * 32 + q * 8];

        float4v o2[2][2];
#pragma unroll
        for (int mt = 0; mt < 2; ++mt)
#pragma unroll
            for (int nt = 0; nt < 2; ++nt) o2[mt][nt] = (float4v){0.f, 0.f, 0.f, 0.f};

#pragma unroll
        for (int mt = 0; mt < 2; ++mt) {
            int m = (wv * 2 + mt) * 16 + l15;
            const short* yb = &U[YB_OFF + m * YB_STRIDE + q * 8];
#pragma unroll
            for (int ks = 0; ks < 3; ++ks) {
                short8 af = *(const short8*)(yb + ks * 32);
#pragma unroll
                for (int nt = 0; nt < 2; ++nt)
                    o2[mt][nt] = __builtin_amdgcn_mfma_f32_16x16x32_bf16(
                        af, b2[nt][ks], o2[mt][nt], 0, 0, 0);
            }
        }

        // store out[n, cc, t0+tl, w]
#pragma unroll
        for (int mt = 0; mt < 2; ++mt) {
#pragma unroll
            for (int nt = 0; nt < 2; ++nt) {
                int w = nt * 16 + l15;
                if (w < V_) {
#pragma unroll
                    for (int i = 0; i < 4; ++i) {
                        int m  = (wv * 2 + mt) * 16 + q * 4 + i;
                        int cc = m & 63, tl = m >> 6;
                        out[((size_t)(n * COUT_ + cc) * T_ + (t0 + tl)) * V_ + w] = o2[mt][nt][i];
                    }
                }
            }
        }

        // ---- chunk tail: convert tmp + publish XB(h+1) (safe after B1) ----
        if (stage_ok) {
#pragma unroll
            for (int s = 0; s < UPT; ++s) {
                int u = tid + s * 256;
                if (u < SUNITS) {
                    int col2 = u % 25, cg = u / 25;
                    short8 a, b;
#pragma unroll
                    for (int j = 0; j < 8; ++j) {
                        a[j] = (short)bf16r(tmp[s][j].x);
                        b[j] = (short)bf16r(tmp[s][j].y);
                    }
                    *(short8*)&U[(col2 * 2 + 0) * XB_STRIDE + cg * 8] = a;
                    *(short8*)&U[(col2 * 2 + 1) * XB_STRIDE + cg * 8] = b;
                }
            }
        }
    }

    // flush ybar: each thread's racc2[j][ct][i] -> ysum[n][o][v] (col<50 only).
    // Exactly 2 threads collide per (o,v) (the two tl's); lanes in a q-group
    // write 16 consecutive floats -> decent coalescing.
    float* yb = ysum + (size_t)n * NYV;
#pragma unroll
    for (int ct = 0; ct < NCT; ++ct) {
        int col = ct * 16 + l15;
        if (col < NCOLS) {
            int v = (col >= V_) ? col - V_ : col;
#pragma unroll
            for (int j = 0; j < 3; ++j) {
                int obase = (rt0 + j) * 16 + q * 4;
#pragma unroll
                for (int i = 0; i < 4; ++i)
                    atomicAdd(&yb[(obase + i) * V_ + v], racc2[j][ct][i]);
            }
        }
    }
}

// ---------- e2: x1m/x2m -> sem -> graphs; block = (n, 10 j's x 25 v) ------------
// ysum holds raw sum over t; the 1/T mean-scale is folded in at the end.
__global__ __launch_bounds__(256) void e2_graphs(const float* __restrict__ ysum,
                                                 const float* __restrict__ W1,
                                                 const float* __restrict__ b1,
                                                 const float* __restrict__ W2,
                                                 const float* __restrict__ b2,
                                                 const int* __restrict__ node_type,
                                                 float* __restrict__ out) {
    __shared__ float s1[10][V_];
    __shared__ float sem[10];
    const int tid = threadIdx.x;
    const int n  = blockIdx.x >> 5;
    const int jc = blockIdx.x & 31;
    const int jl = tid / V_;
    const int v  = tid - jl * V_;
    const int j  = jc * 10 + jl;
    float x2 = 0.f;
    if (jl < 10) {
        const float* yb = ysum + (size_t)n * NYV + v;
        const float* w1 = W1 + j * OC_;
        const float* w2 = W2 + j * OC_;
        float a1 = 0.f, a2 = 0.f;
        for (int o = 0; o < OC_; ++o) {
            float yv = yb[o * V_];
            a1 += w1[o] * yv;
            a2 += w2[o] * yv;
        }
        s1[jl][v] = b1[j] + a1 * (1.0f / T_);
        x2 = b2[j] + a2 * (1.0f / T_);
    }
    __syncthreads();
    if (tid < 10) {
        int s = (jc * 10 + tid) >> 6;   // semantic index = j / 64
        float sum = 0.f, cnt = 0.f;
        for (int vv = 0; vv < V_; ++vv)
            if (node_type[vv] == s) { sum += s1[tid][vv]; cnt += 1.f; }
        sem[tid] = sum / cnt;
    }
    __syncthreads();
    if (jl < 10)
        out[OUT_OFF_G + (size_t)n * (SS_ * COUT_ * V_) + j * V_ + v] = sem[jl] - x2;
}

extern "C" void kernel_launch(void* const* d_in, const int* in_sizes, int n_in,
                              void* d_out, int out_size, void* d_ws, size_t ws_size,
                              hipStream_t stream) {
    const float* x         = (const float*)d_in[0];
    const float* A         = (const float*)d_in[1];
    const int*   node_type = (const int*)d_in[2];
    const float* Wc        = (const float*)d_in[3];
    const float* bc        = (const float*)d_in[4];
    const float* W1        = (const float*)d_in[5];
    const float* b1        = (const float*)d_in[6];
    const float* W2        = (const float*)d_in[7];
    const float* b2        = (const float*)d_in[8];
    float* out = (float*)d_out;

    float* ysum = (float*)d_ws;                    // 307200 floats (atomic target)
    short* WcB  = (short*)(ysum + N_ * NYV);       // 36864 shorts
    short* A2T  = WcB + OC_ * CIN_;                // 3328 shorts

    // prep grid must cover ysum zeroing: N_*NYV = 307200 -> 1200 blocks
    hipLaunchKernelGGL(prep, dim3((N_ * NYV + 255) / 256), dim3(256), 0, stream,
                       Wc, A, WcB, A2T, ysum, out);
    hipLaunchKernelGGL(fused_mfma, dim3(NBLK), dim3(256), 0, stream,
                       x, WcB, bc, A2T, out, ysum);
    hipLaunchKernelGGL(e2_graphs, dim3(N_ * 32), dim3(256), 0, stream,
                       ysum, W1, b1, W2, b2, node_type, out);
}

// Round 10
// 566.667 us; speedup vs baseline: 1.1918x; 1.1918x over previous
//
#include <hip/hip_runtime.h>

#define N_    64
#define CIN_  192
#define T_    256
#define V_    25
#define K_    3
#define COUT_ 64
#define OC_   192
#define SS_   5

#define OUT_OFF_A (N_*COUT_*T_*V_)          // 26214400
#define OUT_OFF_G (OUT_OFF_A + K_*V_*V_)    // 26216275

#define TCH   2              // t's per inner chunk
#define HCH   16             // chunks per block -> 32 t's per block
#define NCOLS 50             // TCH*V_
#define NCT   4              // 16-col tiles in GEMM1 (50 -> pad 64)
#define XB_STRIDE 200        // shorts per XB row (192 + 8 pad)
#define XB_ROWS 64           // NCT*16 (rows 50..63 stay zero from init)
#define XB_SH  (XB_ROWS*XB_STRIDE)            // 12800 shorts (single buffer)
#define YB_STRIDE 104        // shorts per YB row (75 -> pad 96 -> 104)
#define YB_ROWS 128          // TCH*64
#define YB_OFF  XB_SH
#define U_SHORTS (YB_OFF + YB_ROWS*YB_STRIDE) // 26112 shorts = 52224 B
#define NYV  4800            // OC_*V_ : per-n ybar size
#define CPN  (T_/(TCH*HCH))  // 8 chunk-blocks per n
#define NBLK (N_*CPN)        // 512 fused blocks = exactly 2/CU, one round
#define SUNITS (25*(CIN_/8)) // 600 staging units per chunk (col-pair x 8-ch group)
#define UPT 3                // ceil(SUNITS/256) units per thread

// Barrier that does NOT drain vmcnt: each wave drains its own LDS ops
// (lgkmcnt(0)) so producer ds_writes are visible after s_barrier, but
// in-flight global loads/stores stay outstanding across the barrier.
// sched_barrier(0) on both sides pins memory ops (rule #18).
#define BAR_LDS() do {                                          \
    __builtin_amdgcn_sched_barrier(0);                          \
    asm volatile("s_waitcnt lgkmcnt(0)" ::: "memory");          \
    __builtin_amdgcn_s_barrier();                               \
    __builtin_amdgcn_sched_barrier(0);                          \
} while (0)

typedef __attribute__((ext_vector_type(8))) short short8;
typedef __attribute__((ext_vector_type(4))) float float4v;

__device__ inline unsigned bf16r(float f) {            // fp32 -> bf16 RNE
    unsigned u = __float_as_uint(f);
    return (u + 0x7fffu + ((u >> 16) & 1u)) >> 16;
}

// ---------- prep: WcB (bf16), A2T (Acat^T, bf16, zero-padded), A copy, ysum=0 --
__global__ __launch_bounds__(256) void prep(const float* __restrict__ Wc,
                                            const float* __restrict__ A,
                                            short* __restrict__ WcB,
                                            short* __restrict__ A2T,
                                            float* __restrict__ ysum,
                                            float* __restrict__ out) {
    int idx = blockIdx.x * 256 + threadIdx.x;
    if (idx < OC_ * CIN_) WcB[idx] = (short)bf16r(Wc[idx]);
    if (idx < 32 * YB_STRIDE) {           // A2T[w][kk], kk = k*25+v, zeros elsewhere
        int w = idx / YB_STRIDE, kk = idx - w * YB_STRIDE;
        short val = 0;
        if (w < V_ && kk < K_ * V_) {
            int k = kk / V_, v = kk - k * V_;
            val = (short)bf16r(A[k * V_ * V_ + v * V_ + w]);
        }
        A2T[idx] = val;
    }
    if (idx < K_ * V_ * V_) out[OUT_OFF_A + idx] = A[idx];
    if (idx < N_ * NYV) ysum[idx] = 0.f;  // atomic accumulation target for fused
}

// ---------- fused MFMA: y = Wc@x+bc, out = Ycat@Acat, ybar sums via atomics ----
// CHAMPION structure (570.9 us): pinned prefetch after B0 (sched_barrier),
// lgkmcnt-only barriers (vmem in flight across B0/B1), wfrag resident, scalar
// partials racc[19], coalesced atomic flush. R7-R9 deltas all reverted
// (each regressed: setprio starved the co-block's prefetch; vec-partials and
// in-reg ybar both blew the register envelope -> spill balloon).
// R10 single delta vs champion: b2 served from LDS (A2l staged once) instead
// of per-chunk L2 loads — register-neutral, removes exposed L2 latency before
// the GEMM2 MFMAs. LDS 52224 -> 58880 B, still 2 blocks/CU.
// Pad-correctness: A2T cols [75,96) are exact zeros; XB rows 50..63 / YB pad
// cols keep the one-time zero init or finite bf16.
__global__ __launch_bounds__(256, 2) void fused_mfma(const float* __restrict__ x,
                                                     const short* __restrict__ WcB,
                                                     const float* __restrict__ bc,
                                                     const short* __restrict__ A2T,
                                                     float* __restrict__ out,
                                                     float* __restrict__ ysum) {
    __shared__ __align__(16) short U[U_SHORTS];
    __shared__ __align__(16) short A2l[32 * YB_STRIDE];

    const int tid  = threadIdx.x;
    const int lane = tid & 63;
    const int wv   = tid >> 6;
    const int l15  = lane & 15;
    const int q    = lane >> 4;
    const int n    = blockIdx.x >> 3;
    const int tc   = blockIdx.x & 7;
    const int rt0  = wv * 3;

    // one-time zero of U + stage A2l (both published by the syncthreads below)
    {
        int4 z = make_int4(0, 0, 0, 0);
        for (int i = tid; i < U_SHORTS / 8; i += 256) ((int4*)U)[i] = z;
        for (int i = tid; i < 32 * YB_STRIDE / 2; i += 256)
            ((int*)A2l)[i] = ((const int*)A2T)[i];
    }
    __syncthreads();

    // Wc A-fragments resident in registers (72 VGPR): wave wv owns rows [wv*48,+48)
    short8 wfrag[3][6];
    {
        const short* wb = WcB + (rt0 * 16 + l15) * CIN_ + q * 8;
#pragma unroll
        for (int j = 0; j < 3; ++j)
#pragma unroll
            for (int ks = 0; ks < 6; ++ks)
                wfrag[j][ks] = *(const short8*)(wb + j * 16 * CIN_ + ks * 32);
    }
    float4v bvec[3];
#pragma unroll
    for (int j = 0; j < 3; ++j)
        bvec[j] = *(const float4v*)(bc + (rt0 + j) * 16 + q * 4);

    float racc[19];
#pragma unroll
    for (int u = 0; u < 19; ++u) racc[u] = 0.f;

    const float* xn = x + (size_t)n * (CIN_ * T_ * V_);
    const int tbase = tc * (TCH * HCH);

    // prologue: stage chunk 0 (synchronous, once per block)
    for (int u = tid; u < SUNITS; u += 256) {
        int col2 = u % 25, cg = u / 25;
        const float* xp = xn + (size_t)(cg * 8) * (T_ * V_) + tbase * V_ + col2 * 2;
        short8 a, b;
#pragma unroll
        for (int j = 0; j < 8; ++j) {
            float2 f = *(const float2*)(xp + (size_t)j * (T_ * V_));
            a[j] = (short)bf16r(f.x);
            b[j] = (short)bf16r(f.y);
        }
        *(short8*)&U[(col2 * 2 + 0) * XB_STRIDE + cg * 8] = a;
        *(short8*)&U[(col2 * 2 + 1) * XB_STRIDE + cg * 8] = b;
    }

    for (int h = 0; h < HCH; ++h) {
        const int t0 = tbase + h * TCH;
        const bool stage_ok = (h < HCH - 1);

        BAR_LDS();         // B0: XB(h) ready; YB(h-1) readers done

        // ---- prefetch: issue chunk h+1's 24 global loads NOW, pinned ----
        float2 tmp[UPT][8];
        if (stage_ok) {
#pragma unroll
            for (int s = 0; s < UPT; ++s) {
                int u = tid + s * 256;
                if (u < SUNITS) {
                    int col2 = u % 25, cg = u / 25;
                    const float* xp = xn + (size_t)(cg * 8) * (T_ * V_) + (t0 + TCH) * V_ + col2 * 2;
#pragma unroll
                    for (int j = 0; j < 8; ++j)
                        tmp[s][j] = *(const float2*)(xp + (size_t)j * (T_ * V_));
                }
            }
            __builtin_amdgcn_sched_barrier(0);   // loads may not sink past here
        }

        // ---- GEMM1: acc[j][ct], K=192=6*32, wfrag resident ----
        float4v acc[3][NCT];
#pragma unroll
        for (int j = 0; j < 3; ++j)
#pragma unroll
            for (int ct = 0; ct < NCT; ++ct) acc[j][ct] = bvec[j];

#pragma unroll
        for (int ct = 0; ct < NCT; ++ct) {
            const short* xb = &U[(ct * 16 + l15) * XB_STRIDE + q * 8];
#pragma unroll
            for (int ks = 0; ks < 6; ++ks) {
                short8 bfrag = *(const short8*)(xb + ks * 32);
#pragma unroll
                for (int j = 0; j < 3; ++j)
                    acc[j][ct] = __builtin_amdgcn_mfma_f32_16x16x32_bf16(
                        wfrag[j][ks], bfrag, acc[j][ct], 0, 0, 0);
            }
        }

        // ---- Ywrite: acc -> YB[(tl*64+cc)][k*25+v] (pad cols stay zero) ----
#pragma unroll
        for (int ct = 0; ct < NCT; ++ct) {
            int col = ct * 16 + l15;
            if (col < NCOLS) {
                int tl = col / V_;
                int v  = col - tl * V_;
#pragma unroll
                for (int j = 0; j < 3; ++j) {
                    int obase = (rt0 + j) * 16 + q * 4;
#pragma unroll
                    for (int i = 0; i < 4; ++i) {
                        int o   = obase + i;
                        int row = tl * 64 + (o & 63);
                        int cY  = (o >> 6) * V_ + v;
                        U[YB_OFF + row * YB_STRIDE + cY] = (short)bf16r(acc[j][ct][i]);
                    }
                }
            }
        }

        BAR_LDS();         // B1: YB(h) published; XB(h) readers done; vmem flies on

        // ---- GEMM2: Out[(t,cc)=128][w pad 32] = Ycat[128][pad96] @ Acat ----
        // b2 from LDS (A2l): register-neutral, no L2 latency on the MFMA path
        short8 b2[2][3];
#pragma unroll
        for (int nt = 0; nt < 2; ++nt)
#pragma unroll
            for (int ks = 0; ks < 3; ++ks)
                b2[nt][ks] = *(const short8*)&A2l[(nt * 16 + l15) * YB_STRIDE + ks * 32 + q * 8];

        float4v o2[2][2];
#pragma unroll
        for (int mt = 0; mt < 2; ++mt)
#pragma unroll
            for (int nt = 0; nt < 2; ++nt) o2[mt][nt] = (float4v){0.f, 0.f, 0.f, 0.f};

#pragma unroll
        for (int mt = 0; mt < 2; ++mt) {
            int m = (wv * 2 + mt) * 16 + l15;
            const short* yb = &U[YB_OFF + m * YB_STRIDE + q * 8];
#pragma unroll
            for (int ks = 0; ks < 3; ++ks) {
                short8 af = *(const short8*)(yb + ks * 32);
#pragma unroll
                for (int nt = 0; nt < 2; ++nt)
                    o2[mt][nt] = __builtin_amdgcn_mfma_f32_16x16x32_bf16(
                        af, b2[nt][ks], o2[mt][nt], 0, 0, 0);
            }
        }

        // store out[n, cc, t0+tl, w]
#pragma unroll
        for (int mt = 0; mt < 2; ++mt) {
#pragma unroll
            for (int nt = 0; nt < 2; ++nt) {
                int w = nt * 16 + l15;
                if (w < V_) {
#pragma unroll
                    for (int i = 0; i < 4; ++i) {
                        int m  = (wv * 2 + mt) * 16 + q * 4 + i;
                        int cc = m & 63, tl = m >> 6;
                        out[((size_t)(n * COUT_ + cc) * T_ + (t0 + tl)) * V_ + w] = o2[mt][nt][i];
                    }
                }
            }
        }

        // ---- y t-partials from YB: racc[u] += sum_tl y[o, tl, v] ----
#pragma unroll
        for (int u = 0; u < 19; ++u) {
            int idx = tid + u * 256;
            if (u < 18 || idx < NYV) {
                int o = idx / V_, v = idx - (idx / V_) * V_;
                int cc = o & 63, k = o >> 6;
                const short* yp = &U[YB_OFF + cc * YB_STRIDE + k * V_ + v];
                float s = 0.f;
#pragma unroll
                for (int tl = 0; tl < TCH; ++tl) {
                    unsigned b = (unsigned short)yp[tl * 64 * YB_STRIDE];
                    s += __uint_as_float(b << 16);
                }
                racc[u] += s;
            }
        }

        // ---- chunk tail: convert tmp + publish XB(h+1) (safe after B1) ----
        if (stage_ok) {
#pragma unroll
            for (int s = 0; s < UPT; ++s) {
                int u = tid + s * 256;
                if (u < SUNITS) {
                    int col2 = u % 25, cg = u / 25;
                    short8 a, b;
#pragma unroll
                    for (int j = 0; j < 8; ++j) {
                        a[j] = (short)bf16r(tmp[s][j].x);
                        b[j] = (short)bf16r(tmp[s][j].y);
                    }
                    *(short8*)&U[(col2 * 2 + 0) * XB_STRIDE + cg * 8] = a;
                    *(short8*)&U[(col2 * 2 + 1) * XB_STRIDE + cg * 8] = b;
                }
            }
        }
    }

    // flush per-block partials: atomic accumulate into ysum[n] (coalesced)
    float* yb = ysum + (size_t)n * NYV;
#pragma unroll
    for (int u = 0; u < 19; ++u) {
        int idx = tid + u * 256;
        if (u < 18 || idx < NYV) atomicAdd(&yb[idx], racc[u]);
    }
}

// ---------- e2: x1m/x2m -> sem -> graphs; block = (n, 10 j's x 25 v) ------------
// ysum holds raw sum over t; the 1/T mean-scale is folded in at the end.
__global__ __launch_bounds__(256) void e2_graphs(const float* __restrict__ ysum,
                                                 const float* __restrict__ W1,
                                                 const float* __restrict__ b1,
                                                 const float* __restrict__ W2,
                                                 const float* __restrict__ b2,
                                                 const int* __restrict__ node_type,
                                                 float* __restrict__ out) {
    __shared__ float s1[10][V_];
    __shared__ float sem[10];
    const int tid = threadIdx.x;
    const int n  = blockIdx.x >> 5;
    const int jc = blockIdx.x & 31;
    const int jl = tid / V_;
    const int v  = tid - jl * V_;
    const int j  = jc * 10 + jl;
    float x2 = 0.f;
    if (jl < 10) {
        const float* yb = ysum + (size_t)n * NYV + v;
        const float* w1 = W1 + j * OC_;
        const float* w2 = W2 + j * OC_;
        float a1 = 0.f, a2 = 0.f;
        for (int o = 0; o < OC_; ++o) {
            float yv = yb[o * V_];
            a1 += w1[o] * yv;
            a2 += w2[o] * yv;
        }
        s1[jl][v] = b1[j] + a1 * (1.0f / T_);
        x2 = b2[j] + a2 * (1.0f / T_);
    }
    __syncthreads();
    if (tid < 10) {
        int s = (jc * 10 + tid) >> 6;   // semantic index = j / 64
        float sum = 0.f, cnt = 0.f;
        for (int vv = 0; vv < V_; ++vv)
            if (node_type[vv] == s) { sum += s1[tid][vv]; cnt += 1.f; }
        sem[tid] = sum / cnt;
    }
    __syncthreads();
    if (jl < 10)
        out[OUT_OFF_G + (size_t)n * (SS_ * COUT_ * V_) + j * V_ + v] = sem[jl] - x2;
}

extern "C" void kernel_launch(void* const* d_in, const int* in_sizes, int n_in,
                              void* d_out, int out_size, void* d_ws, size_t ws_size,
                              hipStream_t stream) {
    const float* x         = (const float*)d_in[0];
    const float* A         = (const float*)d_in[1];
    const int*   node_type = (const int*)d_in[2];
    const float* Wc        = (const float*)d_in[3];
    const float* bc        = (const float*)d_in[4];
    const float* W1        = (const float*)d_in[5];
    const float* b1        = (const float*)d_in[6];
    const float* W2        = (const float*)d_in[7];
    const float* b2        = (const float*)d_in[8];
    float* out = (float*)d_out;

    float* ysum = (float*)d_ws;                    // 307200 floats (atomic target)
    short* WcB  = (short*)(ysum + N_ * NYV);       // 36864 shorts
    short* A2T  = WcB + OC_ * CIN_;                // 3328 shorts

    // prep grid must cover ysum zeroing: N_*NYV = 307200 -> 1200 blocks
    hipLaunchKernelGGL(prep, dim3((N_ * NYV + 255) / 256), dim3(256), 0, stream,
                       Wc, A, WcB, A2T, ysum, out);
    hipLaunchKernelGGL(fused_mfma, dim3(NBLK), dim3(256), 0, stream,
                       x, WcB, bc, A2T, out, ysum);
    hipLaunchKernelGGL(e2_graphs, dim3(N_ * 32), dim3(256), 0, stream,
                       ysum, W1, b1, W2, b2, node_type, out);
}

// Round 11
// 555.357 us; speedup vs baseline: 1.2161x; 1.0204x over previous
//
#include <hip/hip_runtime.h>

#define N_    64
#define CIN_  192
#define T_    256
#define V_    25
#define K_    3
#define COUT_ 64
#define OC_   192
#define SS_   5

#define OUT_OFF_A (N_*COUT_*T_*V_)          // 26214400
#define OUT_OFF_G (OUT_OFF_A + K_*V_*V_)    // 26216275

#define TCH   2              // t's per inner chunk
#define HCH   16             // chunks per block -> 32 t's per block
#define NCOLS 50             // TCH*V_ ; col = 2*v + tl (v-major)
#define NCT   4              // 16-col tiles in GEMM1 (50 -> pad 64)
#define XB_STRIDE 200        // shorts per XB row (192 + 8 pad)
#define XB_ROWS 64           // NCT*16 (rows 50..63 stay zero from init)
#define XB_SH  (XB_ROWS*XB_STRIDE)            // 12800 shorts (single buffer)
#define YB_STRIDE 104        // shorts per YB row; col kk = k*32+v (pad 96 -> 104)
#define YB_ROWS 128          // TCH*64
#define YB_OFF  XB_SH
#define U_SHORTS (YB_OFF + YB_ROWS*YB_STRIDE) // 26112 shorts = 52224 B
#define NYV  4800            // OC_*V_ : per-n ybar size
#define CPN  (T_/(TCH*HCH))  // 8 chunk-blocks per n
#define NBLK (N_*CPN)        // 512 fused blocks = exactly 2/CU, one round
#define SUNITS (25*(CIN_/8)) // 600 staging units per chunk (flat-pair x 8-ch group)
#define UPT 3                // ceil(SUNITS/256) units per thread

// Barrier that does NOT drain vmcnt: each wave drains its own LDS ops
// (lgkmcnt(0)) so producer ds_writes are visible after s_barrier, but
// in-flight global loads/stores stay outstanding across the barrier.
// sched_barrier(0) on both sides pins memory ops (rule #18).
#define BAR_LDS() do {                                          \
    __builtin_amdgcn_sched_barrier(0);                          \
    asm volatile("s_waitcnt lgkmcnt(0)" ::: "memory");          \
    __builtin_amdgcn_s_barrier();                               \
    __builtin_amdgcn_sched_barrier(0);                          \
} while (0)

typedef __attribute__((ext_vector_type(8))) short short8;
typedef __attribute__((ext_vector_type(4))) float float4v;

__device__ inline unsigned bf16r(float f) {            // fp32 -> bf16 RNE
    unsigned u = __float_as_uint(f);
    return (u + 0x7fffu + ((u >> 16) & 1u)) >> 16;
}

// flat (t,v) index f in [0,50) -> XB column 2*v + tl
__device__ inline int ncol(int f) {
    return (f < 25) ? f * 2 : (f - 25) * 2 + 1;
}

// ---------- prep: WcB (bf16), A2T (Acat^T, kk=k*32+v, zero-padded), ysum=0 ----
__global__ __launch_bounds__(256) void prep(const float* __restrict__ Wc,
                                            const float* __restrict__ A,
                                            short* __restrict__ WcB,
                                            short* __restrict__ A2T,
                                            float* __restrict__ ysum,
                                            float* __restrict__ out) {
    int idx = blockIdx.x * 256 + threadIdx.x;
    if (idx < OC_ * CIN_) WcB[idx] = (short)bf16r(Wc[idx]);
    if (idx < 32 * YB_STRIDE) {           // A2T[w][kk], kk = k*32+v, zeros elsewhere
        int w = idx / YB_STRIDE, kk = idx - w * YB_STRIDE;
        short val = 0;
        if (w < V_ && kk < 96) {
            int k = kk >> 5, v = kk & 31;
            if (v < V_) val = (short)bf16r(A[k * V_ * V_ + v * V_ + w]);
        }
        A2T[idx] = val;
    }
    if (idx < K_ * V_ * V_) out[OUT_OFF_A + idx] = A[idx];
    if (idx < N_ * NYV) ysum[idx] = 0.f;  // atomic accumulation target for fused
}

// ---------- fused MFMA: y = Wc@x+bc, out = Ycat@Acat, ybar sums via atomics ----
// Champion structure (R10, 566.7us): pinned prefetch after B0, lgkmcnt-only
// barriers, wfrag resident, A2l LDS-staged, scalar partials racc[19],
// coalesced atomic flush.
// R11 delta (register-neutral): GEMM1 operands SWAPPED -> output transposed so
// each lane's 4 acc regs are 4 consecutive XB-columns at FIXED o. With v-major
// XB columns (col=2v+tl) and YB columns kk=k*32+v, Ywrite packs into 24
// aligned ds_write_b32 (was 48 scalar ds_write_b16). Fragment loads unchanged
// (A-row and B-col fragments share the same lane layout). Bias becomes 3
// per-lane scalars (swapped output: o = (rt0+j)*16 + l15, fixed per lane).
// Pad-correctness: A2T slots v in [25,32) and kk >= 96 are exact zeros; XB
// rows 50..63 and YB pad slots keep the one-time zero init; every product
// against them is 0.
__global__ __launch_bounds__(256, 2) void fused_mfma(const float* __restrict__ x,
                                                     const short* __restrict__ WcB,
                                                     const float* __restrict__ bc,
                                                     const short* __restrict__ A2T,
                                                     float* __restrict__ out,
                                                     float* __restrict__ ysum) {
    __shared__ __align__(16) short U[U_SHORTS];
    __shared__ __align__(16) short A2l[32 * YB_STRIDE];

    const int tid  = threadIdx.x;
    const int lane = tid & 63;
    const int wv   = tid >> 6;
    const int l15  = lane & 15;
    const int q    = lane >> 4;
    const int n    = blockIdx.x >> 3;
    const int tc   = blockIdx.x & 7;
    const int rt0  = wv * 3;

    // one-time zero of U + stage A2l (both published by the syncthreads below)
    {
        int4 z = make_int4(0, 0, 0, 0);
        for (int i = tid; i < U_SHORTS / 8; i += 256) ((int4*)U)[i] = z;
        for (int i = tid; i < 32 * YB_STRIDE / 2; i += 256)
            ((int*)A2l)[i] = ((const int*)A2T)[i];
    }
    __syncthreads();

    // Wc fragments resident (72 VGPR): as B-operand, lane l15 picks o-column
    short8 wfrag[3][6];
    {
        const short* wb = WcB + (rt0 * 16 + l15) * CIN_ + q * 8;
#pragma unroll
        for (int j = 0; j < 3; ++j)
#pragma unroll
            for (int ks = 0; ks < 6; ++ks)
                wfrag[j][ks] = *(const short8*)(wb + j * 16 * CIN_ + ks * 32);
    }
    // bias per lane: o = (rt0+j)*16 + l15 fixed -> scalar per j
    float bcs[3];
#pragma unroll
    for (int j = 0; j < 3; ++j) bcs[j] = bc[(rt0 + j) * 16 + l15];

    float racc[19];
#pragma unroll
    for (int u = 0; u < 19; ++u) racc[u] = 0.f;

    const float* xn = x + (size_t)n * (CIN_ * T_ * V_);
    const int tbase = tc * (TCH * HCH);

    // prologue: stage chunk 0 (synchronous, once per block)
    for (int u = tid; u < SUNITS; u += 256) {
        int f0 = (u % 25) * 2, cg = u / 25;
        const float* xp = xn + (size_t)(cg * 8) * (T_ * V_) + tbase * V_ + f0;
        short8 a, b;
#pragma unroll
        for (int j = 0; j < 8; ++j) {
            float2 f = *(const float2*)(xp + (size_t)j * (T_ * V_));
            a[j] = (short)bf16r(f.x);
            b[j] = (short)bf16r(f.y);
        }
        *(short8*)&U[ncol(f0) * XB_STRIDE + cg * 8] = a;
        *(short8*)&U[ncol(f0 + 1) * XB_STRIDE + cg * 8] = b;
    }

    for (int h = 0; h < HCH; ++h) {
        const int t0 = tbase + h * TCH;
        const bool stage_ok = (h < HCH - 1);

        BAR_LDS();         // B0: XB(h) ready; YB(h-1) readers done

        // ---- prefetch: issue chunk h+1's 24 global loads NOW, pinned ----
        float2 tmp[UPT][8];
        if (stage_ok) {
#pragma unroll
            for (int s = 0; s < UPT; ++s) {
                int u = tid + s * 256;
                if (u < SUNITS) {
                    int f0 = (u % 25) * 2, cg = u / 25;
                    const float* xp = xn + (size_t)(cg * 8) * (T_ * V_) + (t0 + TCH) * V_ + f0;
#pragma unroll
                    for (int j = 0; j < 8; ++j)
                        tmp[s][j] = *(const float2*)(xp + (size_t)j * (T_ * V_));
                }
            }
            __builtin_amdgcn_sched_barrier(0);   // loads may not sink past here
        }

        // ---- GEMM1 (swapped): acc[j][ct] = (Wc@x)^T tile, K=192=6*32 ----
        float4v acc[3][NCT];
#pragma unroll
        for (int j = 0; j < 3; ++j)
#pragma unroll
            for (int ct = 0; ct < NCT; ++ct)
                acc[j][ct] = (float4v){bcs[j], bcs[j], bcs[j], bcs[j]};

#pragma unroll
        for (int ct = 0; ct < NCT; ++ct) {
            const short* xb = &U[(ct * 16 + l15) * XB_STRIDE + q * 8];
#pragma unroll
            for (int ks = 0; ks < 6; ++ks) {
                short8 bfrag = *(const short8*)(xb + ks * 32);
#pragma unroll
                for (int j = 0; j < 3; ++j)
                    acc[j][ct] = __builtin_amdgcn_mfma_f32_16x16x32_bf16(
                        bfrag, wfrag[j][ks], acc[j][ct], 0, 0, 0);
            }
        }

        // ---- Ywrite (packed): lane holds cols colbase..+3 at fixed o ----
        // col = 2v+tl: regs (0,2) -> row tl=0 @ v0,v0+1 ; regs (1,3) -> row tl=1
#pragma unroll
        for (int j = 0; j < 3; ++j) {
            int o  = (rt0 + j) * 16 + l15;
            int cc = o & 63, k = o >> 6;
            int r0 = YB_OFF + cc * YB_STRIDE + k * 32;           // tl=0 row base
            int r1 = r0 + 64 * YB_STRIDE;                        // tl=1 row base
#pragma unroll
            for (int ct = 0; ct < NCT; ++ct) {
                int colbase = ct * 16 + q * 4;   // even
                int v0 = colbase >> 1;           // even
                if (colbase <= 44) {
                    unsigned p0 = bf16r(acc[j][ct][0]) | (bf16r(acc[j][ct][2]) << 16);
                    unsigned p1 = bf16r(acc[j][ct][1]) | (bf16r(acc[j][ct][3]) << 16);
                    *(unsigned*)&U[r0 + v0] = p0;
                    *(unsigned*)&U[r1 + v0] = p1;
                } else if (colbase == 48) {      // cols 48,49 = (v24,tl0),(v24,tl1)
                    U[r0 + 24] = (short)bf16r(acc[j][ct][0]);
                    U[r1 + 24] = (short)bf16r(acc[j][ct][1]);
                }
            }
        }

        BAR_LDS();         // B1: YB(h) published; XB(h) readers done; vmem flies on

        // ---- GEMM2: Out[(t,cc)=128][w pad 32] = Ycat[128][pad96] @ Acat ----
        short8 b2[2][3];
#pragma unroll
        for (int nt = 0; nt < 2; ++nt)
#pragma unroll
            for (int ks = 0; ks < 3; ++ks)
                b2[nt][ks] = *(const short8*)&A2l[(nt * 16 + l15) * YB_STRIDE + ks * 32 + q * 8];

        float4v o2[2][2];
#pragma unroll
        for (int mt = 0; mt < 2; ++mt)
#pragma unroll
            for (int nt = 0; nt < 2; ++nt) o2[mt][nt] = (float4v){0.f, 0.f, 0.f, 0.f};

#pragma unroll
        for (int mt = 0; mt < 2; ++mt) {
            int m = (wv * 2 + mt) * 16 + l15;
            const short* yb = &U[YB_OFF + m * YB_STRIDE + q * 8];
#pragma unroll
            for (int ks = 0; ks < 3; ++ks) {
                short8 af = *(const short8*)(yb + ks * 32);
#pragma unroll
                for (int nt = 0; nt < 2; ++nt)
                    o2[mt][nt] = __builtin_amdgcn_mfma_f32_16x16x32_bf16(
                        af, b2[nt][ks], o2[mt][nt], 0, 0, 0);
            }
        }

        // store out[n, cc, t0+tl, w]
#pragma unroll
        for (int mt = 0; mt < 2; ++mt) {
#pragma unroll
            for (int nt = 0; nt < 2; ++nt) {
                int w = nt * 16 + l15;
                if (w < V_) {
#pragma unroll
                    for (int i = 0; i < 4; ++i) {
                        int m  = (wv * 2 + mt) * 16 + q * 4 + i;
                        int cc = m & 63, tl = m >> 6;
                        out[((size_t)(n * COUT_ + cc) * T_ + (t0 + tl)) * V_ + w] = o2[mt][nt][i];
                    }
                }
            }
        }

        // ---- y t-partials from YB: racc[u] += sum_tl y[o, tl, v] ----
#pragma unroll
        for (int u = 0; u < 19; ++u) {
            int idx = tid + u * 256;
            if (u < 18 || idx < NYV) {
                int o = idx / V_, v = idx - (idx / V_) * V_;
                int cc = o & 63, k = o >> 6;
                const short* yp = &U[YB_OFF + cc * YB_STRIDE + k * 32 + v];
                float s = 0.f;
#pragma unroll
                for (int tl = 0; tl < TCH; ++tl) {
                    unsigned b = (unsigned short)yp[tl * 64 * YB_STRIDE];
                    s += __uint_as_float(b << 16);
                }
                racc[u] += s;
            }
        }

        // ---- chunk tail: convert tmp + publish XB(h+1) (safe after B1) ----
        if (stage_ok) {
#pragma unroll
            for (int s = 0; s < UPT; ++s) {
                int u = tid + s * 256;
                if (u < SUNITS) {
                    int f0 = (u % 25) * 2, cg = u / 25;
                    short8 a, b;
#pragma unroll
                    for (int j = 0; j < 8; ++j) {
                        a[j] = (short)bf16r(tmp[s][j].x);
                        b[j] = (short)bf16r(tmp[s][j].y);
                    }
                    *(short8*)&U[ncol(f0) * XB_STRIDE + cg * 8] = a;
                    *(short8*)&U[ncol(f0 + 1) * XB_STRIDE + cg * 8] = b;
                }
            }
        }
    }

    // flush per-block partials: atomic accumulate into ysum[n] (coalesced)
    float* yb = ysum + (size_t)n * NYV;
#pragma unroll
    for (int u = 0; u < 19; ++u) {
        int idx = tid + u * 256;
        if (u < 18 || idx < NYV) atomicAdd(&yb[idx], racc[u]);
    }
}

// ---------- e2: x1m/x2m -> sem -> graphs; block = (n, 10 j's x 25 v) ------------
// ysum holds raw sum over t; the 1/T mean-scale is folded in at the end.
__global__ __launch_bounds__(256) void e2_graphs(const float* __restrict__ ysum,
                                                 const float* __restrict__ W1,
                                                 const float* __restrict__ b1,
                                                 const float* __restrict__ W2,
                                                 const float* __restrict__ b2,
                                                 const int* __restrict__ node_type,
                                                 float* __restrict__ out) {
    __shared__ float s1[10][V_];
    __shared__ float sem[10];
    const int tid = threadIdx.x;
    const int n  = blockIdx.x >> 5;
    const int jc = blockIdx.x & 31;
    const int jl = tid / V_;
    const int v  = tid - jl * V_;
    const int j  = jc * 10 + jl;
    float x2 = 0.f;
    if (jl < 10) {
        const float* yb = ysum + (size_t)n * NYV + v;
        const float* w1 = W1 + j * OC_;
        const float* w2 = W2 + j * OC_;
        float a1 = 0.f, a2 = 0.f;
        for (int o = 0; o < OC_; ++o) {
            float yv = yb[o * V_];
            a1 += w1[o] * yv;
            a2 += w2[o] * yv;
        }
        s1[jl][v] = b1[j] + a1 * (1.0f / T_);
        x2 = b2[j] + a2 * (1.0f / T_);
    }
    __syncthreads();
    if (tid < 10) {
        int s = (jc * 10 + tid) >> 6;   // semantic index = j / 64
        float sum = 0.f, cnt = 0.f;
        for (int vv = 0; vv < V_; ++vv)
            if (node_type[vv] == s) { sum += s1[tid][vv]; cnt += 1.f; }
        sem[tid] = sum / cnt;
    }
    __syncthreads();
    if (jl < 10)
        out[OUT_OFF_G + (size_t)n * (SS_ * COUT_ * V_) + j * V_ + v] = sem[jl] - x2;
}

extern "C" void kernel_launch(void* const* d_in, const int* in_sizes, int n_in,
                              void* d_out, int out_size, void* d_ws, size_t ws_size,
                              hipStream_t stream) {
    const float* x         = (const float*)d_in[0];
    const float* A         = (const float*)d_in[1];
    const int*   node_type = (const int*)d_in[2];
    const float* Wc        = (const float*)d_in[3];
    const float* bc        = (const float*)d_in[4];
    const float* W1        = (const float*)d_in[5];
    const float* b1        = (const float*)d_in[6];
    const float* W2        = (const float*)d_in[7];
    const float* b2        = (const float*)d_in[8];
    float* out = (float*)d_out;

    float* ysum = (float*)d_ws;                    // 307200 floats (atomic target)
    short* WcB  = (short*)(ysum + N_ * NYV);       // 36864 shorts
    short* A2T  = WcB + OC_ * CIN_;                // 3328 shorts

    // prep grid must cover ysum zeroing: N_*NYV = 307200 -> 1200 blocks
    hipLaunchKernelGGL(prep, dim3((N_ * NYV + 255) / 256), dim3(256), 0, stream,
                       Wc, A, WcB, A2T, ysum, out);
    hipLaunchKernelGGL(fused_mfma, dim3(NBLK), dim3(256), 0, stream,
                       x, WcB, bc, A2T, out, ysum);
    hipLaunchKernelGGL(e2_graphs, dim3(N_ * 32), dim3(256), 0, stream,
                       ysum, W1, b1, W2, b2, node_type, out);
}